// Round 14
// baseline (2105.016 us; speedup 1.0000x reference)
//
#include <hip/hip_runtime.h>
#include <math.h>

// Problem constants
#define CB 16
#define CS 400
#define CT 51
#define CTM1 50
#define CV 50000
#define CE 128
#define CH 256
#define CMAXOOV 50
#define CEXT (CV + CMAXOOV)
#define CX 640             // gate GEMM K = [emb(128)|ctx(256)|h(256)]
#define NST 16             // state blocks
#define NGT 16             // gate blocks (4 batch-groups x 4 unit-slices)
#define NWK 223            // vocab worker blocks
#define NBLK 256
#define NTILE 782          // ceil(V/64)

typedef __attribute__((ext_vector_type(4))) float f32x4;
typedef __attribute__((ext_vector_type(8))) short short8;
typedef unsigned int U32;
typedef unsigned long long U64;

__device__ __forceinline__ float wave_sum(float x) {
#pragma unroll
  for (int o = 32; o > 0; o >>= 1) x += __shfl_xor(x, o);
  return x;
}
__device__ __forceinline__ float sigm(float x) {
  return 1.f / (1.f + __expf(-x));
}
__device__ __forceinline__ float ftanh(float x) {
  x = fminf(fmaxf(x, -15.f), 15.f);
  float e = __expf(2.f * x);
  return (e - 1.f) / (e + 1.f);
}
__device__ __forceinline__ unsigned short f2bf(float f) {
  union { float f; U32 u; } x;
  x.f = f;
  U32 r = x.u + 0x7FFFu + ((x.u >> 16) & 1u);  // RNE
  return (unsigned short)(r >> 16);
}
__device__ __forceinline__ float bf2f(unsigned short u) {
  return __uint_as_float(((U32)u) << 16);
}
__device__ __forceinline__ U64 pack4(float a, float b, float c, float d) {
  return (U64)f2bf(a) | ((U64)f2bf(b) << 16) | ((U64)f2bf(c) << 32) |
         ((U64)f2bf(d) << 48);
}
// uncached (device-coherent) ops — flags + producer-side publishes ONLY
__device__ __forceinline__ U32 ald32(const U32* p) {
  return __hip_atomic_load(p, __ATOMIC_RELAXED, __HIP_MEMORY_SCOPE_AGENT);
}
__device__ __forceinline__ void ast32(U32* p, U32 v) {
  __hip_atomic_store(p, v, __ATOMIC_RELAXED, __HIP_MEMORY_SCOPE_AGENT);
}
__device__ __forceinline__ void astf(float* p, float v) {
  __hip_atomic_store((U32*)p, __float_as_uint(v), __ATOMIC_RELAXED,
                     __HIP_MEMORY_SCOPE_AGENT);
}
__device__ __forceinline__ void ast64(U64* p, U64 v) {
  __hip_atomic_store(p, v, __ATOMIC_RELAXED, __HIP_MEMORY_SCOPE_AGENT);
}
#define VM0 asm volatile("s_waitcnt vmcnt(0)" ::: "memory")

// ---------------------------------------------------------------------------
// One-time weight prep
// ---------------------------------------------------------------------------
__global__ __launch_bounds__(256) void pw_convert(
    const float* __restrict__ W, unsigned short* __restrict__ Wb) {
  size_t i = ((size_t)blockIdx.x * 256 + threadIdx.x) * 8;
  float4 a = *(const float4*)(W + i);
  float4 b = *(const float4*)(W + i + 4);
  short8 o;
  o[0] = (short)f2bf(a.x); o[1] = (short)f2bf(a.y);
  o[2] = (short)f2bf(a.z); o[3] = (short)f2bf(a.w);
  o[4] = (short)f2bf(b.x); o[5] = (short)f2bf(b.y);
  o[6] = (short)f2bf(b.z); o[7] = (short)f2bf(b.w);
  *(short8*)(Wb + i) = o;
}

// Wcat[j][k] bf16 row-major [1024][640]: k<384 -> W_ih[j][k], else W_hh.
__global__ __launch_bounds__(256) void pw_cat(
    const float* __restrict__ W_ih, const float* __restrict__ W_hh,
    unsigned short* __restrict__ Wcat) {
  int t8 = blockIdx.x * 256 + threadIdx.x;  // 81920 short8
  int j = t8 / 80, k8 = t8 % 80;
  short8 o;
#pragma unroll
  for (int i = 0; i < 8; ++i) {
    int k = k8 * 8 + i;
    float v = (k < CE + CH) ? W_ih[(size_t)j * (CE + CH) + k]
                            : W_hh[(size_t)j * CH + (k - (CE + CH))];
    o[i] = (short)f2bf(v);
  }
  *(short8*)(Wcat + (size_t)t8 * 8) = o;
}

__global__ __launch_bounds__(256) void pw_t256(const float* __restrict__ in,
                                               float* __restrict__ out) {
  int j = blockIdx.x, k = threadIdx.x;
  out[j * CH + k] = in[k * CH + j];
}

__global__ __launch_bounds__(256) void pw_t256_bf16(
    const float* __restrict__ in, unsigned short* __restrict__ out) {
  int j = blockIdx.x, k = threadIdx.x;
  out[j * CH + k] = f2bf(in[k * CH + j]);
}

__global__ __launch_bounds__(256) void pw_cvt16(
    const float* __restrict__ in, unsigned short* __restrict__ out) {
  size_t i = ((size_t)blockIdx.x * 256 + threadIdx.x) * 8;
  float4 a = *(const float4*)(in + i);
  float4 b = *(const float4*)(in + i + 4);
  short8 o;
  o[0] = (short)f2bf(a.x); o[1] = (short)f2bf(a.y);
  o[2] = (short)f2bf(a.z); o[3] = (short)f2bf(a.w);
  o[4] = (short)f2bf(b.x); o[5] = (short)f2bf(b.y);
  o[6] = (short)f2bf(b.z); o[7] = (short)f2bf(b.w);
  *(short8*)(out + i) = o;
}

// ---------------------------------------------------------------------------
// P0: Wh_h16 (bf16) = enc @ W_h^T; copy_idx.
// ---------------------------------------------------------------------------
__global__ __launch_bounds__(256) void p0_precompute(
    const float* __restrict__ enc, const float* __restrict__ W_hT,
    const int* __restrict__ src_ids, const int* __restrict__ src_oov,
    unsigned short* __restrict__ Wh_h16, int* __restrict__ copy_idx) {
  const int row0 = blockIdx.x * 8, tid = threadIdx.x;
  __shared__ float erT[CH * 8];
#pragma unroll
  for (int i = 0; i < 8; ++i) {
    int idx = tid + i * 256;
    int r = idx >> 8, j = idx & 255;
    erT[j * 8 + r] = enc[(size_t)row0 * CH + idx];
  }
  if (tid < 8) {
    int row = row0 + tid;
    int ov = src_oov[row];
    copy_idx[row] = (ov >= 0) ? (CV + ov) : src_ids[row];
  }
  __syncthreads();
  float acc[8] = {0, 0, 0, 0, 0, 0, 0, 0};
#pragma unroll 4
  for (int j = 0; j < CH; ++j) {
    float w = W_hT[j * CH + tid];
    float4 e0 = *(const float4*)&erT[j * 8];
    float4 e1 = *(const float4*)&erT[j * 8 + 4];
    acc[0] += e0.x * w; acc[1] += e0.y * w; acc[2] += e0.z * w; acc[3] += e0.w * w;
    acc[4] += e1.x * w; acc[5] += e1.y * w; acc[6] += e1.z * w; acc[7] += e1.w * w;
  }
#pragma unroll
  for (int r = 0; r < 8; ++r)
    Wh_h16[(size_t)(row0 + r) * CH + tid] = f2bf(acc[r]);
}

// ---------------------------------------------------------------------------
// Z: zero control words + rowsum partials.
// ctrl: release@256 (64x16) | xrdy@1280 (16x16) | grdy@1536 (16x16)
// ---------------------------------------------------------------------------
__global__ __launch_bounds__(256) void z_init(U32* __restrict__ ctrl,
                                              float* __restrict__ part) {
  int tid = blockIdx.x * 256 + threadIdx.x;
  if (tid < 2048) ctrl[tid] = 0u;
  for (int i = tid; i < CTM1 * CB * 64; i += 256 * 64) part[i] = 0.f;
}

// ---------------------------------------------------------------------------
// MEGA: 16 state + 16 gate (4x4 tiling, own cell + hws/pgen partials)
//       + 1 agg + 223 vocab workers.
// ---------------------------------------------------------------------------
__global__ __launch_bounds__(1024, 4) void mega(
    const int* __restrict__ tgt, const float* __restrict__ hidden,
    const float* __restrict__ cell, const int* __restrict__ src_lens,
    const float* __restrict__ embedding, const float* __restrict__ w_c,
    const float* __restrict__ v_vec, const float* __restrict__ b_attn,
    const float* __restrict__ b_ih, const float* __restrict__ b_hh,
    const float* __restrict__ W_pg, const float* __restrict__ b_pg,
    const float* __restrict__ b_out,
    const unsigned short* __restrict__ Wh_h16,
    const unsigned short* __restrict__ enc16,
    const unsigned short* __restrict__ W_sT16,
    const unsigned short* __restrict__ Wcat,
    const unsigned short* __restrict__ Wb, U64* __restrict__ A64,
    float* __restrict__ HexF, float* __restrict__ HwsP,
    float* __restrict__ PgP, unsigned short* __restrict__ attn16,
    float* __restrict__ p_gen_g, float* __restrict__ part,
    float* __restrict__ covloss_b, U32* __restrict__ ctrl,
    float* __restrict__ dout) {
  const int bid = blockIdx.x, tid = threadIdx.x;
  const int lane = tid & 63, wv = tid >> 6;  // 16 waves
  U32* release = ctrl + 256;    // 64 worker replicas
  U32* xrdy = ctrl + 1280;      // state: ctx published
  U32* grdy = ctrl + 1536;      // gate: h/hws/pgen slices published

  __shared__ __align__(16) U64 sh_big[2592];
  __shared__ float cov_s[CS];
  __shared__ float a_s[CS];
  __shared__ __align__(16) float h_cur[CH];   // gate: h_sl[4][64]
  __shared__ float hws_s[CH];
  __shared__ __align__(16) float ctx_s[CH];
  __shared__ float emb_s[CE];
  __shared__ float pctx[4 * CH];
  __shared__ float gsl[4][4][64];             // gate: [g2][b][u_loc]
  __shared__ int sh_tok[CB];
  __shared__ float red[16];
  __shared__ float stat[4];
  __shared__ float prs[16][16];

  if (bid < NST) {
    // ================= STATE LANE (batch b), 16 waves =================
    const int b = bid;
    const int gi = b >> 2;  // batch group
    const int len = src_lens[b];
    const float ba = b_attn[0];
    const int k4 = lane * 4;
    const float4 wc4 = *(const float4*)(w_c + k4);
    const float4 vv4 = *(const float4*)(v_vec + k4);
    const int kg = tid & 255, grp = tid >> 8;
    float covl = 0.f;

    if (tid < CS) cov_s[tid] = 0.f;
    if (tid < CH) h_cur[tid] = hidden[b * CH + tid];
    __syncthreads();
    {  // one-time hWs init from h0
      float acc = 0.f;
#pragma unroll 8
      for (int j = grp * 64; j < grp * 64 + 64; ++j)
        acc += h_cur[j] * bf2f(W_sT16[j * CH + kg]);
      pctx[grp * CH + kg] = acc;
    }
    __syncthreads();
    if (tid < CH)
      hws_s[tid] = pctx[tid] + pctx[CH + tid] + pctx[2 * CH + tid] +
                   pctx[3 * CH + tid];
    __syncthreads();

    for (int t = 0; t < CTM1; ++t) {
      // ---- phase A ----
      if (t > 0) {
        if (tid < CS) {
          float a = a_s[tid], cv = cov_s[tid];
          covl += fminf(a, cv);
          cov_s[tid] = cv + a;
        }
        __syncthreads();
      }
      float ps = 0.f;
      for (int s = wv; s < CS; s += 16) {
        float cv = cov_s[s];
        U64 wq = *(const U64*)(Wh_h16 + ((size_t)(b * CS + s)) * CH + k4);
        float p =
            ftanh(bf2f((unsigned short)wq) + hws_s[k4] + cv * wc4.x + ba) *
                vv4.x +
            ftanh(bf2f((unsigned short)(wq >> 16)) + hws_s[k4 + 1] +
                  cv * wc4.y + ba) *
                vv4.y +
            ftanh(bf2f((unsigned short)(wq >> 32)) + hws_s[k4 + 2] +
                  cv * wc4.z + ba) *
                vv4.z +
            ftanh(bf2f((unsigned short)(wq >> 48)) + hws_s[k4 + 3] +
                  cv * wc4.w + ba) *
                vv4.w;
        p = wave_sum(p);
        if (lane == 0) {
          float e = (s < len) ? __expf(p) : 0.f;  // |score| <~ 10: safe
          a_s[s] = e;
          ps += e;
        }
      }
      if (lane == 0) red[wv] = ps;
      __syncthreads();
      if (tid == 0) {
        float s2 = 0.f;
#pragma unroll
        for (int i = 0; i < 16; ++i) s2 += red[i];
        stat[0] = 1.f / s2;
      }
      __syncthreads();
      const float inv = stat[0];
      if (tid < CS) {
        float a = a_s[tid] * inv;
        a_s[tid] = a;
        attn16[((size_t)t * CB + b) * CS + tid] = f2bf(a);
      }
      __syncthreads();
      {  // ctx partials
        float pc = 0.f;
        const unsigned short* er =
            enc16 + ((size_t)(b * CS + grp * 100)) * CH + kg;
#pragma unroll 10
        for (int i = 0; i < 100; ++i)
          pc += a_s[grp * 100 + i] * bf2f(er[(size_t)i * CH]);
        pctx[grp * CH + kg] = pc;
      }
      __syncthreads();
      if (tid < CH)
        ctx_s[tid] = pctx[tid] + pctx[CH + tid] + pctx[2 * CH + tid] +
                     pctx[3 * CH + tid];
      if (tid < CE)
        emb_s[tid] = embedding[(size_t)tgt[b * CT + t] * CE + tid];
      __syncthreads();
      if (tid < 64) {  // publish ctx -> A64 ctx-half (UC)
        ast64(&A64[(size_t)t * 2048 + b * 128 + 64 + tid],
              pack4(ctx_s[4 * tid], ctx_s[4 * tid + 1], ctx_s[4 * tid + 2],
                    ctx_s[4 * tid + 3]));
      }
      VM0;
      __syncthreads();
      if (tid == 0) ast32(&xrdy[b * 16], (U32)(t + 1));
      // overlapped: ctx/emb part of p_gen
      {
        float z = 0.f;
        if (tid < CH) z = ctx_s[tid] * W_pg[CH + tid];
        if (tid < CE) z += emb_s[tid] * W_pg[2 * CH + tid];
        z = wave_sum(z);
        if (lane == 0) red[wv] = z;
      }
      __syncthreads();
      // ---- wait own-group gate slices ----
      if (wv == 0) {
        int gg = 0;
        while (gg < (1 << 22)) {
          U32 v = (lane < 4) ? ald32(&grdy[(gi * 4 + lane) * 16])
                             : (U32)(t + 1);
          if (__all(v >= (U32)(t + 1))) break;
          __builtin_amdgcn_s_sleep(1);
          ++gg;
        }
      }
      __syncthreads();
      // ---- phase C: sum hws partials + finish p_gen ----
      if (tid < CH) {
        const float* hp = HwsP + (((size_t)t * CB + b) * 4) * CH + tid;
        hws_s[tid] = hp[0] + hp[CH] + hp[2 * CH] + hp[3 * CH];
      }
      if (tid == 0) {
        float s2 = 0.f;
#pragma unroll
        for (int i = 0; i < 16; ++i) s2 += red[i];
        const float* pp = PgP + ((size_t)t * CB + b) * 4;
        s2 += pp[0] + pp[1] + pp[2] + pp[3];
        p_gen_g[t * CB + b] = sigm(s2 + b_pg[0]);
      }
      __syncthreads();
    }
    // tail: covloss t=49 + totals + hT
    if (tid < CS) covl += fminf(a_s[tid], cov_s[tid]);
    covl = wave_sum(covl);
    if (lane == 0) red[wv] = covl;
    __syncthreads();
    if (tid == 0) {
      float s2 = 0.f;
#pragma unroll
      for (int i = 0; i < 16; ++i) s2 += red[i];
      covloss_b[b] = s2;
    }
    if (tid < CH) {
      const size_t D0 = (size_t)CB * CTM1 * CEXT;
      dout[D0 + b * CH + tid] = HexF[((size_t)49 * CB + b) * CH + tid];
    }
  } else if (bid < NST + NGT) {
    // ===== GATE BLOCKS (i=batch group, j=unit slice of 64 units) =====
    const int g = bid - NST;
    const int gi = g >> 2, gj = g & 3;
    const int b0 = gi * 4, u0 = gj * 64;
    const int nn = lane & 15, gq = lane >> 4;
    U64* xg64 = sh_big;                  // rows [4][162] u64 (= [4][648] sh)
    short* xg_s = (short*)sh_big;
    const short8* x8 = (const short8*)sh_big;
    // wave-wise MFMA col mapping: local col c = wv*16+nn
    const int g2 = wv >> 2;
    const int ncol = g2 * 256 + u0 + (wv & 3) * 16 + nn;
    const short8* bp = (const short8*)Wcat + (size_t)ncol * 80;
    // cell-thread mapping: wave cw<4 -> batch cw, lane -> unit
    const int cbL = wv, cu = lane;       // valid when wv<4
    float c_reg = 0.f, bi0 = 0.f, bi1 = 0.f, bi2 = 0.f, bi3 = 0.f;
    if (wv < 4) {
      c_reg = cell[(b0 + cbL) * CH + u0 + cu];
      bi0 = b_ih[u0 + cu] + b_hh[u0 + cu];
      bi1 = b_ih[CH + u0 + cu] + b_hh[CH + u0 + cu];
      bi2 = b_ih[2 * CH + u0 + cu] + b_hh[2 * CH + u0 + cu];
      bi3 = b_ih[3 * CH + u0 + cu] + b_hh[3 * CH + u0 + cu];
    }
    for (int t = 0; t < CTM1; ++t) {
      // -- precompute window (overlaps state phase A) --
      if (t > 0 && wv == 0) {  // own group's h(t-1) slices visible?
        int gg = 0;
        while (gg < (1 << 22)) {
          U32 v = (lane < 4) ? ald32(&grdy[(gi * 4 + lane) * 16]) : (U32)t;
          if (__all(v >= (U32)t)) break;
          __builtin_amdgcn_s_sleep(1);
          ++gg;
        }
      }
      if (tid < 4) sh_tok[tid] = tgt[(b0 + tid) * CT + t];
      __syncthreads();
      // stage emb(t) + h(t-1) for 4 batches
      // x row layout (shorts): emb 0..127 | ctx 128..383 | h 384..639
      //                (u64):  emb 0..31  | ctx 32..95   | h 96..159
      if (tid < 512) {
        int bb = tid >> 7, k = tid & 127;
        xg_s[bb * 648 + k] =
            (short)f2bf(embedding[(size_t)sh_tok[bb] * CE + k]);
      }
      if (t == 0) {
        if (tid < 1024) {
          int bb = tid >> 8, k = tid & 255;
          xg_s[bb * 648 + 384 + k] = (short)f2bf(hidden[(b0 + bb) * CH + k]);
        }
      } else {
        if (tid < 256) {
          int bb = tid >> 6, iu = tid & 63;
          xg64[bb * 162 + 96 + iu] =
              A64[(size_t)(t - 1) * 2048 + (b0 + bb) * 128 + iu];
        }
      }
      __syncthreads();
      f32x4 acc = {0.f, 0.f, 0.f, 0.f};
      {  // emb part kt 0..3, h part kt 12..19 (pre-ctx)
#pragma unroll
        for (int kt = 0; kt < 4; ++kt)
          acc = __builtin_amdgcn_mfma_f32_16x16x32_bf16(
              x8[nn * 81 + kt * 4 + gq], bp[kt * 4 + gq], acc, 0, 0, 0);
#pragma unroll
        for (int kt = 12; kt < 20; ++kt)
          acc = __builtin_amdgcn_mfma_f32_16x16x32_bf16(
              x8[nn * 81 + kt * 4 + gq], bp[kt * 4 + gq], acc, 0, 0, 0);
      }
      // -- wait ctx from own group's 4 state blocks --
      if (wv == 0) {
        int gg = 0;
        while (gg < (1 << 22)) {
          U32 v = (lane < 4) ? ald32(&xrdy[(b0 + lane) * 16]) : (U32)(t + 1);
          if (__all(v >= (U32)(t + 1))) break;
          __builtin_amdgcn_s_sleep(1);
          ++gg;
        }
      }
      __syncthreads();
      if (tid < 256) {  // stage ctx (cached; per-t address) at u64 32..95
        int bb = tid >> 6, iu = tid & 63;
        xg64[bb * 162 + 32 + iu] =
            A64[(size_t)t * 2048 + (b0 + bb) * 128 + 64 + iu];
      }
      __syncthreads();
      {  // ctx part kt 4..11
#pragma unroll
        for (int kt = 4; kt < 12; ++kt)
          acc = __builtin_amdgcn_mfma_f32_16x16x32_bf16(
              x8[nn * 81 + kt * 4 + gq], bp[kt * 4 + gq], acc, 0, 0, 0);
        if (gq == 0) {  // valid D rows m=0..3 (batches)
#pragma unroll
          for (int r = 0; r < 4; ++r)
            gsl[g2][r][(wv & 3) * 16 + nn] = acc[r];
        }
      }
      __syncthreads();
      if (wv < 4) {  // cell update + publish h (fp32 + bf16)
        float gi_ = gsl[0][cbL][cu] + bi0;
        float gf = gsl[1][cbL][cu] + bi1;
        float gg2 = gsl[2][cbL][cu] + bi2;
        float go = gsl[3][cbL][cu] + bi3;
        float cn = sigm(gf) * c_reg + sigm(gi_) * ftanh(gg2);
        c_reg = cn;
        float hn = sigm(go) * ftanh(cn);
        h_cur[cbL * 64 + cu] = hn;
        astf(&HexF[((size_t)t * CB + b0 + cbL) * CH + u0 + cu], hn);
        float h1 = __shfl_down(hn, 1);
        float h2 = __shfl_down(hn, 2);
        float h3 = __shfl_down(hn, 3);
        if (!(cu & 3))
          ast64(&A64[(size_t)t * 2048 + (b0 + cbL) * 128 + gj * 16 +
                     (cu >> 2)],
                pack4(hn, h1, h2, h3));
      }
      __syncthreads();
      {  // hws partial over own 64 units: (b,k) per thread
        int bb = tid >> 8, k = tid & 255;
        float acc2 = 0.f;
#pragma unroll 8
        for (int u = 0; u < 64; ++u)
          acc2 += h_cur[bb * 64 + u] * bf2f(W_sT16[(u0 + u) * CH + k]);
        astf(&HwsP[(((size_t)t * CB + b0 + bb) * 4 + gj) * CH + k], acc2);
      }
      if (wv < 4) {  // p_gen partial
        float pp = h_cur[cbL * 64 + cu] * W_pg[u0 + cu];
        pp = wave_sum(pp);
        if (cu == 0)
          astf(&PgP[((size_t)t * CB + b0 + cbL) * 4 + gj], pp);
      }
      VM0;
      __syncthreads();
      if (tid == 0) ast32(&grdy[g * 16], (U32)(t + 1));
    }
    // tail: cT slice
    if (wv < 4) {
      const size_t D0 = (size_t)CB * CTM1 * CEXT;
      dout[D0 + CB * CH + (b0 + cbL) * CH + u0 + cu] = c_reg;
    }
  } else if (bid == NST + NGT) {
    // ===================== AGGREGATOR (1 block) ==========================
    for (int t = 0; t < CTM1; ++t) {
      if (wv == 0) {
        int gg = 0;
        while (gg < (1 << 22)) {
          U32 v = (lane < NGT) ? ald32(&grdy[lane * 16]) : (U32)(t + 1);
          if (__all(v >= (U32)(t + 1))) break;
          __builtin_amdgcn_s_sleep(4);
          ++gg;
        }
      }
      __syncthreads();
      if (tid < 64) ast32(&release[tid * 16], (U32)(t + 1));
      __syncthreads();
    }
  } else {
    // ============ VOCAB WORKERS (223 blocks, 16 waves, 4 tiles) ==========
    const int vb = bid - NST - NGT - 1;
    const int rep = vb & 63;
    const int nn = lane & 15, g = lane >> 4;
    const int t4 = (wv >> 2) * NWK + vb;
    const int v = t4 * 64 + (wv & 3) * 16 + nn;
    const bool live = (t4 < NTILE) && (v < CV);
    const int vc = live ? v : CV - 1;
    U64* a64l = sh_big;  // [16][130] u64
    const short8* lds8 = (const short8*)sh_big;
    const short8* bp = (const short8*)Wb + (size_t)vc * 64;
    const float bo = live ? b_out[v] : 0.f;
    for (int t = 0; t < CTM1; ++t) {
      if (tid == 0) {
        int gg = 0;
        while (ald32(&release[rep * 16]) < (U32)(t + 1) && ++gg < (1 << 18))
          __builtin_amdgcn_s_sleep(32);
      }
      __syncthreads();
      {  // stage A slab cached
        const U64* src = A64 + (size_t)t * 2048;
#pragma unroll
        for (int i = 0; i < 2; ++i) {
          int idx = tid + i * 1024;
          int row = idx >> 7, col = idx & 127;
          a64l[row * 130 + col] = src[idx];
        }
      }
      __syncthreads();
      short8 af[16];
#pragma unroll
      for (int kt = 0; kt < 16; ++kt) af[kt] = lds8[nn * 65 + kt * 4 + g];
      f32x4 acc = {0.f, 0.f, 0.f, 0.f};
#pragma unroll
      for (int kt = 0; kt < 16; ++kt)
        acc = __builtin_amdgcn_mfma_f32_16x16x32_bf16(af[kt], bp[kt * 4 + g],
                                                      acc, 0, 0, 0);
      float ev[4];
#pragma unroll
      for (int r = 0; r < 4; ++r) {
        float e = live ? __expf(acc[r] + bo) : 0.f;
        if (live) dout[((size_t)((g * 4 + r) * CTM1 + t)) * CEXT + v] = e;
#pragma unroll
        for (int o = 1; o < 16; o <<= 1) e += __shfl_xor(e, o);
        ev[r] = e;
      }
      if (nn == 0) {
#pragma unroll
        for (int r = 0; r < 4; ++r) prs[wv][g * 4 + r] = ev[r];
      }
      __syncthreads();
      if (tid < 16) {
        float s = 0.f;
#pragma unroll
        for (int w = 0; w < 16; ++w) s += prs[w][tid];
        atomicAdd(&part[((size_t)t * CB + tid) * 64 + rep], s);
      }
      __syncthreads();
    }
  }
}

// ---------------------------------------------------------------------------
// POST 1: per (b,t) row: reduce 64 rowsum partials, normalize + zero pads.
// ---------------------------------------------------------------------------
__global__ __launch_bounds__(256) void post_norm(
    const float* __restrict__ part, const float* __restrict__ p_gen_g,
    float* __restrict__ dout) {
  const int R = blockIdx.x;
  const int b = R / CTM1, t = R % CTM1;
  const int tid = threadIdx.x;
  __shared__ float stat;
  float s = (tid < 64) ? part[((size_t)t * CB + b) * 64 + tid] : 0.f;
  s = wave_sum(s);
  if (tid == 0) stat = p_gen_g[t * CB + b] / s;
  __syncthreads();
  float inv = stat;
  float* drow = dout + (size_t)R * CEXT;
  for (int v = tid; v < CEXT; v += 256)
    drow[v] = (v < CV) ? drow[v] * inv : 0.f;
}

// ---------------------------------------------------------------------------
// POST 2: copy-dist scatter for all t + coverage_loss. grid = 16.
// ---------------------------------------------------------------------------
__global__ __launch_bounds__(256) void post_tail(
    const unsigned short* __restrict__ attn16,
    const float* __restrict__ p_gen_g, const int* __restrict__ copy_idx,
    const float* __restrict__ covloss_b, float* __restrict__ dout) {
  const int b = blockIdx.x, tid = threadIdx.x;
  for (int t = 0; t < CTM1; ++t) {
    float pg1 = 1.f - p_gen_g[t * CB + b];
    const unsigned short* ar = attn16 + ((size_t)t * CB + b) * CS;
    float* drow = dout + ((size_t)(b * CTM1 + t)) * CEXT;
    for (int s = tid; s < CS; s += 256)
      atomicAdd(drow + copy_idx[b * CS + s], pg1 * bf2f(ar[s]));
  }
  if (b == 0 && tid == 0) {
    const size_t D0 = (size_t)CB * CTM1 * CEXT;
    float s = 0.f;
    for (int i = 0; i < CB; ++i) s += covloss_b[i];
    dout[D0 + 2 * CB * CH] = s / (float)(CTM1 * CB);
  }
}

// ---------------------------------------------------------------------------
extern "C" void kernel_launch(void* const* d_in, const int* in_sizes, int n_in,
                              void* d_out, int out_size, void* d_ws,
                              size_t ws_size, hipStream_t stream) {
  const int* tgt = (const int*)d_in[0];
  const float* hidden = (const float*)d_in[1];
  const float* cell = (const float*)d_in[2];
  const float* enc = (const float*)d_in[3];
  const int* src_lens = (const int*)d_in[4];
  const int* src_ids = (const int*)d_in[5];
  const int* src_oov = (const int*)d_in[6];
  const float* embedding = (const float*)d_in[7];
  const float* W_h = (const float*)d_in[8];
  const float* W_s = (const float*)d_in[9];
  const float* w_c = (const float*)d_in[10];
  const float* v_vec = (const float*)d_in[11];
  const float* b_attn = (const float*)d_in[12];
  const float* W_ih = (const float*)d_in[13];
  const float* W_hh = (const float*)d_in[14];
  const float* b_ih = (const float*)d_in[15];
  const float* b_hh = (const float*)d_in[16];
  const float* W_pg = (const float*)d_in[17];
  const float* b_pg = (const float*)d_in[18];
  const float* W_out = (const float*)d_in[19];
  const float* b_out = (const float*)d_in[20];
  float* dout = (float*)d_out;

  // workspace layout (word count before u64 region is even)
  float* ws = (float*)d_ws;
  float* W_hT = ws;                                  // 65,536 f
  float* p_gen_g = W_hT + CH * CH;                   // 800 f
  float* part = p_gen_g + CTM1 * CB;                 // 51,200 f
  float* covloss_b = part + CTM1 * CB * 64;          // 16 f
  float* HexF = covloss_b + 16;                      // 204,800 f
  float* HwsP = HexF + (size_t)CTM1 * CB * CH;       // 819,200 f
  float* PgP = HwsP + (size_t)CTM1 * CB * 4 * CH;    // 3,200 f
  int* copy_idx = (int*)(PgP + CTM1 * CB * 4);       // 6,400 i
  U32* ctrl = (U32*)(copy_idx + CB * CS);            // 2,048 u32
  U64* A64 = (U64*)(ctrl + 2048);                    // 102,400 u64
  unsigned short* attn16 =
      (unsigned short*)(A64 + (size_t)CTM1 * 2048);  // 320,000 sh
  unsigned short* Wh_h16 = attn16 + (size_t)CTM1 * CB * CS;  // 1,638,400 sh
  unsigned short* enc16 = Wh_h16 + (size_t)CB * CS * CH;     // 1,638,400 sh
  unsigned short* W_sT16 = enc16 + (size_t)CB * CS * CH;     // 65,536 sh
  unsigned short* Wcat = W_sT16 + CH * CH;           // 655,360 sh
  unsigned short* Wb = Wcat + (size_t)(4 * CH) * CX; // 25,600,000 sh

  z_init<<<64, 256, 0, stream>>>(ctrl, part);
  pw_convert<<<(CV * 2 * CH) / (256 * 8), 256, 0, stream>>>(W_out, Wb);
  pw_cat<<<((4 * CH) * CX / 8) / 256, 256, 0, stream>>>(W_ih, W_hh, Wcat);
  pw_t256<<<CH, CH, 0, stream>>>(W_h, W_hT);
  pw_t256_bf16<<<CH, CH, 0, stream>>>(W_s, W_sT16);
  pw_cvt16<<<(CB * CS * CH) / (256 * 8), 256, 0, stream>>>(enc, enc16);
  p0_precompute<<<CB * CS / 8, 256, 0, stream>>>(enc, W_hT, src_ids, src_oov,
                                                 Wh_h16, copy_idx);

  void* kargs[] = {
      (void*)&tgt,      (void*)&hidden,    (void*)&cell,    (void*)&src_lens,
      (void*)&embedding,(void*)&w_c,       (void*)&v_vec,   (void*)&b_attn,
      (void*)&b_ih,     (void*)&b_hh,      (void*)&W_pg,    (void*)&b_pg,
      (void*)&b_out,    (void*)&Wh_h16,    (void*)&enc16,   (void*)&W_sT16,
      (void*)&Wcat,     (void*)&Wb,        (void*)&A64,     (void*)&HexF,
      (void*)&HwsP,     (void*)&PgP,       (void*)&attn16,  (void*)&p_gen_g,
      (void*)&part,     (void*)&covloss_b, (void*)&ctrl,    (void*)&dout};
  hipError_t e = hipLaunchCooperativeKernel((const void*)mega, dim3(NBLK),
                                            dim3(1024), kargs, 0, stream);
  if (e != hipSuccess) {
    hipLaunchKernelGGL(mega, dim3(NBLK), dim3(1024), 0, stream, tgt, hidden,
                       cell, src_lens, embedding, w_c, v_vec, b_attn, b_ih,
                       b_hh, W_pg, b_pg, b_out, Wh_h16, enc16, W_sT16, Wcat,
                       Wb, A64, HexF, HwsP, PgP, attn16, p_gen_g, part,
                       covloss_b, ctrl, dout);
  }
  post_norm<<<CB * CTM1, 256, 0, stream>>>(part, p_gen_g, dout);
  post_tail<<<CB, 256, 0, stream>>>(attn16, p_gen_g, copy_idx, covloss_b,
                                    dout);
}

// Round 16
// 1775.559 us; speedup vs baseline: 1.1856x; 1.1856x over previous
//
#include <hip/hip_runtime.h>
#include <math.h>

// Problem constants
#define CB 16
#define CS 400
#define CT 51
#define CTM1 50
#define CV 50000
#define CE 128
#define CH 256
#define CMAXOOV 50
#define CEXT (CV + CMAXOOV)
#define CX 640             // gate GEMM K = [emb(128)|ctx(256)|h(256)]
#define NST 16             // state blocks
#define NGT 16             // gate blocks (4 batch-groups x 4 unit-slices)
#define NWK 223            // vocab worker blocks
#define NBLK 256
#define NTILE 782          // ceil(V/64)

typedef __attribute__((ext_vector_type(4))) float f32x4;
typedef __attribute__((ext_vector_type(8))) short short8;
typedef unsigned int U32;
typedef unsigned long long U64;

__device__ __forceinline__ float wave_sum(float x) {
#pragma unroll
  for (int o = 32; o > 0; o >>= 1) x += __shfl_xor(x, o);
  return x;
}
__device__ __forceinline__ float sigm(float x) {
  return 1.f / (1.f + __expf(-x));
}
__device__ __forceinline__ float ftanh(float x) {
  x = fminf(fmaxf(x, -15.f), 15.f);
  float e = __expf(2.f * x);
  return (e - 1.f) / (e + 1.f);
}
__device__ __forceinline__ unsigned short f2bf(float f) {
  union { float f; U32 u; } x;
  x.f = f;
  U32 r = x.u + 0x7FFFu + ((x.u >> 16) & 1u);  // RNE
  return (unsigned short)(r >> 16);
}
__device__ __forceinline__ float bf2f(unsigned short u) {
  return __uint_as_float(((U32)u) << 16);
}
__device__ __forceinline__ U64 pack4(float a, float b, float c, float d) {
  return (U64)f2bf(a) | ((U64)f2bf(b) << 16) | ((U64)f2bf(c) << 32) |
         ((U64)f2bf(d) << 48);
}
// uncached (device-coherent) ops — flags, publishes, and fresh-critical reads
__device__ __forceinline__ U32 ald32(const U32* p) {
  return __hip_atomic_load(p, __ATOMIC_RELAXED, __HIP_MEMORY_SCOPE_AGENT);
}
__device__ __forceinline__ U64 ald64(const U64* p) {
  return __hip_atomic_load(p, __ATOMIC_RELAXED, __HIP_MEMORY_SCOPE_AGENT);
}
__device__ __forceinline__ void ast32(U32* p, U32 v) {
  __hip_atomic_store(p, v, __ATOMIC_RELAXED, __HIP_MEMORY_SCOPE_AGENT);
}
__device__ __forceinline__ void ast64(U64* p, U64 v) {
  __hip_atomic_store(p, v, __ATOMIC_RELAXED, __HIP_MEMORY_SCOPE_AGENT);
}
#define VM0 asm volatile("s_waitcnt vmcnt(0)" ::: "memory")

// ---------------------------------------------------------------------------
// One-time weight prep
// ---------------------------------------------------------------------------
__global__ __launch_bounds__(256) void pw_convert(
    const float* __restrict__ W, unsigned short* __restrict__ Wb) {
  size_t i = ((size_t)blockIdx.x * 256 + threadIdx.x) * 8;
  float4 a = *(const float4*)(W + i);
  float4 b = *(const float4*)(W + i + 4);
  short8 o;
  o[0] = (short)f2bf(a.x); o[1] = (short)f2bf(a.y);
  o[2] = (short)f2bf(a.z); o[3] = (short)f2bf(a.w);
  o[4] = (short)f2bf(b.x); o[5] = (short)f2bf(b.y);
  o[6] = (short)f2bf(b.z); o[7] = (short)f2bf(b.w);
  *(short8*)(Wb + i) = o;
}

// Wcat[j][k] bf16 row-major [1024][640]: k<384 -> W_ih[j][k], else W_hh.
__global__ __launch_bounds__(256) void pw_cat(
    const float* __restrict__ W_ih, const float* __restrict__ W_hh,
    unsigned short* __restrict__ Wcat) {
  int t8 = blockIdx.x * 256 + threadIdx.x;  // 81920 short8
  int j = t8 / 80, k8 = t8 % 80;
  short8 o;
#pragma unroll
  for (int i = 0; i < 8; ++i) {
    int k = k8 * 8 + i;
    float v = (k < CE + CH) ? W_ih[(size_t)j * (CE + CH) + k]
                            : W_hh[(size_t)j * CH + (k - (CE + CH))];
    o[i] = (short)f2bf(v);
  }
  *(short8*)(Wcat + (size_t)t8 * 8) = o;
}

__global__ __launch_bounds__(256) void pw_t256(const float* __restrict__ in,
                                               float* __restrict__ out) {
  int j = blockIdx.x, k = threadIdx.x;
  out[j * CH + k] = in[k * CH + j];
}

__global__ __launch_bounds__(256) void pw_t256_bf16(
    const float* __restrict__ in, unsigned short* __restrict__ out) {
  int j = blockIdx.x, k = threadIdx.x;
  out[j * CH + k] = f2bf(in[k * CH + j]);
}

__global__ __launch_bounds__(256) void pw_cvt16(
    const float* __restrict__ in, unsigned short* __restrict__ out) {
  size_t i = ((size_t)blockIdx.x * 256 + threadIdx.x) * 8;
  float4 a = *(const float4*)(in + i);
  float4 b = *(const float4*)(in + i + 4);
  short8 o;
  o[0] = (short)f2bf(a.x); o[1] = (short)f2bf(a.y);
  o[2] = (short)f2bf(a.z); o[3] = (short)f2bf(a.w);
  o[4] = (short)f2bf(b.x); o[5] = (short)f2bf(b.y);
  o[6] = (short)f2bf(b.z); o[7] = (short)f2bf(b.w);
  *(short8*)(out + i) = o;
}

// ---------------------------------------------------------------------------
// P0: Wh_h16 (bf16) = enc @ W_h^T; copy_idx.
// ---------------------------------------------------------------------------
__global__ __launch_bounds__(256) void p0_precompute(
    const float* __restrict__ enc, const float* __restrict__ W_hT,
    const int* __restrict__ src_ids, const int* __restrict__ src_oov,
    unsigned short* __restrict__ Wh_h16, int* __restrict__ copy_idx) {
  const int row0 = blockIdx.x * 8, tid = threadIdx.x;
  __shared__ float erT[CH * 8];
#pragma unroll
  for (int i = 0; i < 8; ++i) {
    int idx = tid + i * 256;
    int r = idx >> 8, j = idx & 255;
    erT[j * 8 + r] = enc[(size_t)row0 * CH + idx];
  }
  if (tid < 8) {
    int row = row0 + tid;
    int ov = src_oov[row];
    copy_idx[row] = (ov >= 0) ? (CV + ov) : src_ids[row];
  }
  __syncthreads();
  float acc[8] = {0, 0, 0, 0, 0, 0, 0, 0};
#pragma unroll 4
  for (int j = 0; j < CH; ++j) {
    float w = W_hT[j * CH + tid];
    float4 e0 = *(const float4*)&erT[j * 8];
    float4 e1 = *(const float4*)&erT[j * 8 + 4];
    acc[0] += e0.x * w; acc[1] += e0.y * w; acc[2] += e0.z * w; acc[3] += e0.w * w;
    acc[4] += e1.x * w; acc[5] += e1.y * w; acc[6] += e1.z * w; acc[7] += e1.w * w;
  }
#pragma unroll
  for (int r = 0; r < 8; ++r)
    Wh_h16[(size_t)(row0 + r) * CH + tid] = f2bf(acc[r]);
}

// ---------------------------------------------------------------------------
// Z: zero control words + rowsum partials.
// ctrl: release@256 (64x16) | xrdy@1280 (16x16) | grdy@1536 (16x16)
// ---------------------------------------------------------------------------
__global__ __launch_bounds__(256) void z_init(U32* __restrict__ ctrl,
                                              float* __restrict__ part) {
  int tid = blockIdx.x * 256 + threadIdx.x;
  if (tid < 2048) ctrl[tid] = 0u;
  for (int i = tid; i < CTM1 * CB * 64; i += 256 * 64) part[i] = 0.f;
}

// ---------------------------------------------------------------------------
// MEGA: 16 state + 16 gate (4x4 tiling, minimal critical path)
//       + 1 agg + 223 vocab workers.
// ---------------------------------------------------------------------------
__global__ __launch_bounds__(1024, 4) void mega(
    const int* __restrict__ tgt, const float* __restrict__ hidden,
    const float* __restrict__ cell, const int* __restrict__ src_lens,
    const float* __restrict__ embedding, const float* __restrict__ w_c,
    const float* __restrict__ v_vec, const float* __restrict__ b_attn,
    const float* __restrict__ b_ih, const float* __restrict__ b_hh,
    const float* __restrict__ W_pg, const float* __restrict__ b_pg,
    const float* __restrict__ b_out,
    const unsigned short* __restrict__ Wh_h16,
    const unsigned short* __restrict__ enc16,
    const unsigned short* __restrict__ W_sT16,
    const unsigned short* __restrict__ Wcat,
    const unsigned short* __restrict__ Wb, U64* __restrict__ A64,
    unsigned short* __restrict__ attn16, float* __restrict__ p_gen_g,
    float* __restrict__ part, float* __restrict__ covloss_b,
    U32* __restrict__ ctrl, float* __restrict__ dout) {
  const int bid = blockIdx.x, tid = threadIdx.x;
  const int lane = tid & 63, wv = tid >> 6;  // 16 waves
  U32* release = ctrl + 256;    // 64 worker replicas
  U32* xrdy = ctrl + 1280;      // state: ctx published
  U32* grdy = ctrl + 1536;      // gate: h slice published

  __shared__ __align__(16) U64 sh_big[2592];
  __shared__ float cov_s[CS];
  __shared__ float a_s[CS];
  __shared__ __align__(16) float h_cur[CH];
  __shared__ float hws_s[CH];
  __shared__ __align__(16) float ctx_s[CH];
  __shared__ float emb_s[CE];
  __shared__ float pctx[4 * CH];
  __shared__ float gsl[4][4][64];             // gate: [g2][b][u_loc]
  __shared__ int sh_tok[CB];
  __shared__ float red[16];
  __shared__ float stat[4];
  __shared__ float prs[16][16];

  if (bid < NST) {
    // ================= STATE LANE (batch b), 16 waves =================
    const int b = bid;
    const int gi = b >> 2;  // batch group
    const int len = src_lens[b];
    const float ba = b_attn[0];
    const int k4 = lane * 4;
    const float4 wc4 = *(const float4*)(w_c + k4);
    const float4 vv4 = *(const float4*)(v_vec + k4);
    const int kg = tid & 255, grp = tid >> 8;
    float covl = 0.f;

    if (tid < CS) { cov_s[tid] = 0.f; a_s[tid] = 0.f; }
    if (tid < CH) h_cur[tid] = hidden[b * CH + tid];
    __syncthreads();
    {  // one-time hWs init from h0
      float acc = 0.f;
#pragma unroll 8
      for (int j = grp * 64; j < grp * 64 + 64; ++j)
        acc += h_cur[j] * bf2f(W_sT16[j * CH + kg]);
      pctx[grp * CH + kg] = acc;
    }
    __syncthreads();
    if (tid < CH)
      hws_s[tid] = pctx[tid] + pctx[CH + tid] + pctx[2 * CH + tid] +
                   pctx[3 * CH + tid];
    __syncthreads();

    for (int t = 0; t < CTM1; ++t) {
      // ---- phase A ----
      if (t > 0) {
        if (tid < CS) {
          float a = a_s[tid], cv = cov_s[tid];
          covl += fminf(a, cv);
          cov_s[tid] = cv + a;
        }
        __syncthreads();
      }
      float ps = 0.f;
      for (int s = wv; s < len; s += 16) {  // len-clamped (a_s[>=len]==0)
        float cv = cov_s[s];
        U64 wq = *(const U64*)(Wh_h16 + ((size_t)(b * CS + s)) * CH + k4);
        float p =
            ftanh(bf2f((unsigned short)wq) + hws_s[k4] + cv * wc4.x + ba) *
                vv4.x +
            ftanh(bf2f((unsigned short)(wq >> 16)) + hws_s[k4 + 1] +
                  cv * wc4.y + ba) *
                vv4.y +
            ftanh(bf2f((unsigned short)(wq >> 32)) + hws_s[k4 + 2] +
                  cv * wc4.z + ba) *
                vv4.z +
            ftanh(bf2f((unsigned short)(wq >> 48)) + hws_s[k4 + 3] +
                  cv * wc4.w + ba) *
                vv4.w;
        p = wave_sum(p);
        if (lane == 0) {
          float e = __expf(p);  // |score| <~ 10: no-max softmax safe
          a_s[s] = e;
          ps += e;
        }
      }
      if (lane == 0) red[wv] = ps;
      __syncthreads();
      if (tid == 0) {
        float s2 = 0.f;
#pragma unroll
        for (int i = 0; i < 16; ++i) s2 += red[i];
        stat[0] = 1.f / s2;
      }
      __syncthreads();
      const float inv = stat[0];
      if (tid < CS) {
        float a = a_s[tid] * inv;   // 0 for s>=len
        a_s[tid] = a;
        attn16[((size_t)t * CB + b) * CS + tid] = f2bf(a);
      }
      __syncthreads();
      {  // ctx partials (len-clamped per group)
        float pc = 0.f;
        int hi = len - grp * 100;
        hi = (hi < 0) ? 0 : ((hi > 100) ? 100 : hi);
        const unsigned short* er =
            enc16 + ((size_t)(b * CS + grp * 100)) * CH + kg;
        for (int i = 0; i < hi; ++i)
          pc += a_s[grp * 100 + i] * bf2f(er[(size_t)i * CH]);
        pctx[grp * CH + kg] = pc;
      }
      __syncthreads();
      if (tid < CH)
        ctx_s[tid] = pctx[tid] + pctx[CH + tid] + pctx[2 * CH + tid] +
                     pctx[3 * CH + tid];
      if (tid < CE)
        emb_s[tid] = embedding[(size_t)tgt[b * CT + t] * CE + tid];
      __syncthreads();
      if (tid < 64) {  // publish ctx -> A64 ctx-half (UC)
        ast64(&A64[(size_t)t * 2048 + b * 128 + 64 + tid],
              pack4(ctx_s[4 * tid], ctx_s[4 * tid + 1], ctx_s[4 * tid + 2],
                    ctx_s[4 * tid + 3]));
      }
      VM0;
      __syncthreads();
      if (tid == 0) ast32(&xrdy[b * 16], (U32)(t + 1));
      // ---- wait own-group gate slices (4 flags) ----
      if (wv == 0) {
        int gg = 0;
        while (gg < (1 << 22)) {
          U32 v = (lane < 4) ? ald32(&grdy[(gi * 4 + lane) * 16])
                             : (U32)(t + 1);
          if (__all(v >= (U32)(t + 1))) break;
          __builtin_amdgcn_s_sleep(1);
          ++gg;
        }
      }
      __syncthreads();
      // ---- phase C: stage h from A64 h-half via UC (fresh!), hWs, p_gen ----
      if (tid < 64) {
        U64 v = ald64(&A64[(size_t)t * 2048 + b * 128 + tid]);
        h_cur[4 * tid] = bf2f((unsigned short)v);
        h_cur[4 * tid + 1] = bf2f((unsigned short)(v >> 16));
        h_cur[4 * tid + 2] = bf2f((unsigned short)(v >> 32));
        h_cur[4 * tid + 3] = bf2f((unsigned short)(v >> 48));
      }
      __syncthreads();
      {
        float acc = 0.f;
#pragma unroll 8
        for (int j = grp * 64; j < grp * 64 + 64; ++j)
          acc += h_cur[j] * bf2f(W_sT16[j * CH + kg]);
        pctx[grp * CH + kg] = acc;
      }
      __syncthreads();
      if (tid < CH)
        hws_s[tid] = pctx[tid] + pctx[CH + tid] + pctx[2 * CH + tid] +
                     pctx[3 * CH + tid];
      {
        float z = 0.f;
        if (tid < CH)
          z = h_cur[tid] * W_pg[tid] + ctx_s[tid] * W_pg[CH + tid];
        if (tid < CE) z += emb_s[tid] * W_pg[2 * CH + tid];
        z = wave_sum(z);
        if (lane == 0) red[wv] = z;
        __syncthreads();
        if (tid == 0) {
          float s2 = 0.f;
#pragma unroll
          for (int i = 0; i < 16; ++i) s2 += red[i];
          p_gen_g[t * CB + b] = sigm(s2 + b_pg[0]);
        }
      }
      __syncthreads();
    }
    // tail: covloss t=49 + totals (hT/cT written by gate blocks)
    if (tid < CS) covl += fminf(a_s[tid], cov_s[tid]);
    covl = wave_sum(covl);
    if (lane == 0) red[wv] = covl;
    __syncthreads();
    if (tid == 0) {
      float s2 = 0.f;
#pragma unroll
      for (int i = 0; i < 16; ++i) s2 += red[i];
      covloss_b[b] = s2;
    }
  } else if (bid < NST + NGT) {
    // ===== GATE BLOCKS (i=batch group, j=unit slice of 64 units) =====
    const int g = bid - NST;
    const int gi = g >> 2, gj = g & 3;
    const int b0 = gi * 4, u0 = gj * 64;
    const int nn = lane & 15, gq = lane >> 4;
    U64* xg64 = sh_big;                  // rows [4][162] u64 (= [4][648] sh)
    short* xg_s = (short*)sh_big;
    const short8* x8 = (const short8*)sh_big;
    const int g2 = wv >> 2;
    const int ncol = g2 * 256 + u0 + (wv & 3) * 16 + nn;
    const short8* bp = (const short8*)Wcat + (size_t)ncol * 80;
    const int cbL = wv, cu = lane;       // valid when wv<4
    float c_reg = 0.f, bi0 = 0.f, bi1 = 0.f, bi2 = 0.f, bi3 = 0.f;
    if (wv < 4) {
      c_reg = cell[(b0 + cbL) * CH + u0 + cu];
      bi0 = b_ih[u0 + cu] + b_hh[u0 + cu];
      bi1 = b_ih[CH + u0 + cu] + b_hh[CH + u0 + cu];
      bi2 = b_ih[2 * CH + u0 + cu] + b_hh[2 * CH + u0 + cu];
      bi3 = b_ih[3 * CH + u0 + cu] + b_hh[3 * CH + u0 + cu];
    }
    for (int t = 0; t < CTM1; ++t) {
      // -- precompute window (overlaps state phase A) --
      if (t > 0 && wv == 0) {  // own group's h(t-1) slices visible?
        int gg = 0;
        while (gg < (1 << 22)) {
          U32 v = (lane < 4) ? ald32(&grdy[(gi * 4 + lane) * 16]) : (U32)t;
          if (__all(v >= (U32)t)) break;
          __builtin_amdgcn_s_sleep(1);
          ++gg;
        }
      }
      if (tid < 4) sh_tok[tid] = tgt[(b0 + tid) * CT + t];
      __syncthreads();
      // x row (shorts): emb 0..127 | ctx 128..383 | h 384..639
      //         (u64):  emb 0..31  | ctx 32..95   | h 96..159
      if (tid < 512) {
        int bb = tid >> 7, k = tid & 127;
        xg_s[bb * 648 + k] =
            (short)f2bf(embedding[(size_t)sh_tok[bb] * CE + k]);
      }
      if (t == 0) {
        if (tid < 1024) {
          int bb = tid >> 8, k = tid & 255;
          xg_s[bb * 648 + 384 + k] = (short)f2bf(hidden[(b0 + bb) * CH + k]);
        }
      } else {
        if (tid < 256) {  // stage h(t-1) via UC (fresh) at u64 96..159
          int bb = tid >> 6, iu = tid & 63;
          xg64[bb * 162 + 96 + iu] =
              ald64(&A64[(size_t)(t - 1) * 2048 + (b0 + bb) * 128 + iu]);
        }
      }
      __syncthreads();
      f32x4 acc = {0.f, 0.f, 0.f, 0.f};
      {  // emb part kt 0..3, h part kt 12..19 (pre-ctx)
#pragma unroll
        for (int kt = 0; kt < 4; ++kt)
          acc = __builtin_amdgcn_mfma_f32_16x16x32_bf16(
              x8[nn * 81 + kt * 4 + gq], bp[kt * 4 + gq], acc, 0, 0, 0);
#pragma unroll
        for (int kt = 12; kt < 20; ++kt)
          acc = __builtin_amdgcn_mfma_f32_16x16x32_bf16(
              x8[nn * 81 + kt * 4 + gq], bp[kt * 4 + gq], acc, 0, 0, 0);
      }
      // -- wait ctx from own group's 4 state blocks --
      if (wv == 0) {
        int gg = 0;
        while (gg < (1 << 22)) {
          U32 v = (lane < 4) ? ald32(&xrdy[(b0 + lane) * 16]) : (U32)(t + 1);
          if (__all(v >= (U32)(t + 1))) break;
          __builtin_amdgcn_s_sleep(1);
          ++gg;
        }
      }
      __syncthreads();
      if (tid < 256) {  // stage ctx via UC (fresh) at u64 32..95
        int bb = tid >> 6, iu = tid & 63;
        xg64[bb * 162 + 32 + iu] =
            ald64(&A64[(size_t)t * 2048 + (b0 + bb) * 128 + 64 + iu]);
      }
      __syncthreads();
      {  // ctx part kt 4..11
#pragma unroll
        for (int kt = 4; kt < 12; ++kt)
          acc = __builtin_amdgcn_mfma_f32_16x16x32_bf16(
              x8[nn * 81 + kt * 4 + gq], bp[kt * 4 + gq], acc, 0, 0, 0);
        if (gq == 0) {  // valid D rows m=0..3 (batches)
#pragma unroll
          for (int r = 0; r < 4; ++r)
            gsl[g2][r][(wv & 3) * 16 + nn] = acc[r];
        }
      }
      __syncthreads();
      if (wv < 4) {  // cell update + publish h (bf16 A64; fp32 hT at t=49)
        float gi_ = gsl[0][cbL][cu] + bi0;
        float gf = gsl[1][cbL][cu] + bi1;
        float gg2 = gsl[2][cbL][cu] + bi2;
        float go = gsl[3][cbL][cu] + bi3;
        float cn = sigm(gf) * c_reg + sigm(gi_) * ftanh(gg2);
        c_reg = cn;
        float hn = sigm(go) * ftanh(cn);
        if (t == CTM1 - 1) {  // exact fp32 hT straight to dout
          const size_t D0 = (size_t)CB * CTM1 * CEXT;
          dout[D0 + (b0 + cbL) * CH + u0 + cu] = hn;
        }
        float h1 = __shfl_down(hn, 1);
        float h2 = __shfl_down(hn, 2);
        float h3 = __shfl_down(hn, 3);
        if (!(cu & 3))
          ast64(&A64[(size_t)t * 2048 + (b0 + cbL) * 128 + gj * 16 +
                     (cu >> 2)],
                pack4(hn, h1, h2, h3));
      }
      VM0;
      __syncthreads();
      if (tid == 0) ast32(&grdy[g * 16], (U32)(t + 1));
    }
    // tail: cT slice (exact fp32)
    if (wv < 4) {
      const size_t D0 = (size_t)CB * CTM1 * CEXT;
      dout[D0 + CB * CH + (b0 + cbL) * CH + u0 + cu] = c_reg;
    }
  } else if (bid == NST + NGT) {
    // ===================== AGGREGATOR (1 block) ==========================
    for (int t = 0; t < CTM1; ++t) {
      if (wv == 0) {
        int gg = 0;
        while (gg < (1 << 22)) {
          U32 v = (lane < NGT) ? ald32(&grdy[lane * 16]) : (U32)(t + 1);
          if (__all(v >= (U32)(t + 1))) break;
          __builtin_amdgcn_s_sleep(4);
          ++gg;
        }
      }
      __syncthreads();
      if (tid < 64) ast32(&release[tid * 16], (U32)(t + 1));
      __syncthreads();
    }
  } else {
    // ============ VOCAB WORKERS (223 blocks, 16 waves, 4 tiles) ==========
    const int vb = bid - NST - NGT - 1;
    const int rep = vb & 63;
    const int nn = lane & 15, g = lane >> 4;
    const int t4 = (wv >> 2) * NWK + vb;
    const int v = t4 * 64 + (wv & 3) * 16 + nn;
    const bool live = (t4 < NTILE) && (v < CV);
    const int vc = live ? v : CV - 1;
    U64* a64l = sh_big;  // [16][130] u64
    const short8* lds8 = (const short8*)sh_big;
    const short8* bp = (const short8*)Wb + (size_t)vc * 64;
    const float bo = live ? b_out[v] : 0.f;
    for (int t = 0; t < CTM1; ++t) {
      if (tid == 0) {
        int gg = 0;
        while (ald32(&release[rep * 16]) < (U32)(t + 1) && ++gg < (1 << 18))
          __builtin_amdgcn_s_sleep(32);
      }
      __syncthreads();
      {  // stage A slab cached (validated across r9-r15)
        const U64* src = A64 + (size_t)t * 2048;
#pragma unroll
        for (int i = 0; i < 2; ++i) {
          int idx = tid + i * 1024;
          int row = idx >> 7, col = idx & 127;
          a64l[row * 130 + col] = src[idx];
        }
      }
      __syncthreads();
      short8 af[16];
#pragma unroll
      for (int kt = 0; kt < 16; ++kt) af[kt] = lds8[nn * 65 + kt * 4 + g];
      f32x4 acc = {0.f, 0.f, 0.f, 0.f};
#pragma unroll
      for (int kt = 0; kt < 16; ++kt)
        acc = __builtin_amdgcn_mfma_f32_16x16x32_bf16(af[kt], bp[kt * 4 + g],
                                                      acc, 0, 0, 0);
      float ev[4];
#pragma unroll
      for (int r = 0; r < 4; ++r) {
        float e = live ? __expf(acc[r] + bo) : 0.f;
        if (live) dout[((size_t)((g * 4 + r) * CTM1 + t)) * CEXT + v] = e;
#pragma unroll
        for (int o = 1; o < 16; o <<= 1) e += __shfl_xor(e, o);
        ev[r] = e;
      }
      if (nn == 0) {
#pragma unroll
        for (int r = 0; r < 4; ++r) prs[wv][g * 4 + r] = ev[r];
      }
      __syncthreads();
      if (tid < 16) {
        float s = 0.f;
#pragma unroll
        for (int w = 0; w < 16; ++w) s += prs[w][tid];
        atomicAdd(&part[((size_t)t * CB + tid) * 64 + rep], s);
      }
      __syncthreads();
    }
  }
}

// ---------------------------------------------------------------------------
// POST 1: per (b,t) row: reduce 64 rowsum partials, normalize + zero pads.
// ---------------------------------------------------------------------------
__global__ __launch_bounds__(256) void post_norm(
    const float* __restrict__ part, const float* __restrict__ p_gen_g,
    float* __restrict__ dout) {
  const int R = blockIdx.x;
  const int b = R / CTM1, t = R % CTM1;
  const int tid = threadIdx.x;
  __shared__ float stat;
  float s = (tid < 64) ? part[((size_t)t * CB + b) * 64 + tid] : 0.f;
  s = wave_sum(s);
  if (tid == 0) stat = p_gen_g[t * CB + b] / s;
  __syncthreads();
  float inv = stat;
  float* drow = dout + (size_t)R * CEXT;
  for (int v = tid; v < CEXT; v += 256)
    drow[v] = (v < CV) ? drow[v] * inv : 0.f;
}

// ---------------------------------------------------------------------------
// POST 2: copy-dist scatter for all t + coverage_loss. grid = 16.
// ---------------------------------------------------------------------------
__global__ __launch_bounds__(256) void post_tail(
    const unsigned short* __restrict__ attn16,
    const float* __restrict__ p_gen_g, const int* __restrict__ copy_idx,
    const float* __restrict__ covloss_b, float* __restrict__ dout) {
  const int b = blockIdx.x, tid = threadIdx.x;
  for (int t = 0; t < CTM1; ++t) {
    float pg1 = 1.f - p_gen_g[t * CB + b];
    const unsigned short* ar = attn16 + ((size_t)t * CB + b) * CS;
    float* drow = dout + ((size_t)(b * CTM1 + t)) * CEXT;
    for (int s = tid; s < CS; s += 256)
      atomicAdd(drow + copy_idx[b * CS + s], pg1 * bf2f(ar[s]));
  }
  if (b == 0 && tid == 0) {
    const size_t D0 = (size_t)CB * CTM1 * CEXT;
    float s = 0.f;
    for (int i = 0; i < CB; ++i) s += covloss_b[i];
    dout[D0 + 2 * CB * CH] = s / (float)(CTM1 * CB);
  }
}

// ---------------------------------------------------------------------------
extern "C" void kernel_launch(void* const* d_in, const int* in_sizes, int n_in,
                              void* d_out, int out_size, void* d_ws,
                              size_t ws_size, hipStream_t stream) {
  const int* tgt = (const int*)d_in[0];
  const float* hidden = (const float*)d_in[1];
  const float* cell = (const float*)d_in[2];
  const float* enc = (const float*)d_in[3];
  const int* src_lens = (const int*)d_in[4];
  const int* src_ids = (const int*)d_in[5];
  const int* src_oov = (const int*)d_in[6];
  const float* embedding = (const float*)d_in[7];
  const float* W_h = (const float*)d_in[8];
  const float* W_s = (const float*)d_in[9];
  const float* w_c = (const float*)d_in[10];
  const float* v_vec = (const float*)d_in[11];
  const float* b_attn = (const float*)d_in[12];
  const float* W_ih = (const float*)d_in[13];
  const float* W_hh = (const float*)d_in[14];
  const float* b_ih = (const float*)d_in[15];
  const float* b_hh = (const float*)d_in[16];
  const float* W_pg = (const float*)d_in[17];
  const float* b_pg = (const float*)d_in[18];
  const float* W_out = (const float*)d_in[19];
  const float* b_out = (const float*)d_in[20];
  float* dout = (float*)d_out;

  // workspace layout (word count before u64 region is even)
  float* ws = (float*)d_ws;
  float* W_hT = ws;                                  // 65,536 f
  float* p_gen_g = W_hT + CH * CH;                   // 800 f
  float* part = p_gen_g + CTM1 * CB;                 // 51,200 f
  float* covloss_b = part + CTM1 * CB * 64;          // 16 f
  int* copy_idx = (int*)(covloss_b + 16);            // 6,400 i
  U32* ctrl = (U32*)(copy_idx + CB * CS);            // 2,048 u32
  U64* A64 = (U64*)(ctrl + 2048);                    // 102,400 u64
  unsigned short* attn16 =
      (unsigned short*)(A64 + (size_t)CTM1 * 2048);  // 320,000 sh
  unsigned short* Wh_h16 = attn16 + (size_t)CTM1 * CB * CS;  // 1,638,400 sh
  unsigned short* enc16 = Wh_h16 + (size_t)CB * CS * CH;     // 1,638,400 sh
  unsigned short* W_sT16 = enc16 + (size_t)CB * CS * CH;     // 65,536 sh
  unsigned short* Wcat = W_sT16 + CH * CH;           // 655,360 sh
  unsigned short* Wb = Wcat + (size_t)(4 * CH) * CX; // 25,600,000 sh

  z_init<<<64, 256, 0, stream>>>(ctrl, part);
  pw_convert<<<(CV * 2 * CH) / (256 * 8), 256, 0, stream>>>(W_out, Wb);
  pw_cat<<<((4 * CH) * CX / 8) / 256, 256, 0, stream>>>(W_ih, W_hh, Wcat);
  pw_t256<<<CH, CH, 0, stream>>>(W_h, W_hT);
  pw_t256_bf16<<<CH, CH, 0, stream>>>(W_s, W_sT16);
  pw_cvt16<<<(CB * CS * CH) / (256 * 8), 256, 0, stream>>>(enc, enc16);
  p0_precompute<<<CB * CS / 8, 256, 0, stream>>>(enc, W_hT, src_ids, src_oov,
                                                 Wh_h16, copy_idx);

  void* kargs[] = {
      (void*)&tgt,      (void*)&hidden,    (void*)&cell,    (void*)&src_lens,
      (void*)&embedding,(void*)&w_c,       (void*)&v_vec,   (void*)&b_attn,
      (void*)&b_ih,     (void*)&b_hh,      (void*)&W_pg,    (void*)&b_pg,
      (void*)&b_out,    (void*)&Wh_h16,    (void*)&enc16,   (void*)&W_sT16,
      (void*)&Wcat,     (void*)&Wb,        (void*)&A64,     (void*)&attn16,
      (void*)&p_gen_g,  (void*)&part,      (void*)&covloss_b,(void*)&ctrl,
      (void*)&dout};
  hipError_t e = hipLaunchCooperativeKernel((const void*)mega, dim3(NBLK),
                                            dim3(1024), kargs, 0, stream);
  if (e != hipSuccess) {
    hipLaunchKernelGGL(mega, dim3(NBLK), dim3(1024), 0, stream, tgt, hidden,
                       cell, src_lens, embedding, w_c, v_vec, b_attn, b_ih,
                       b_hh, W_pg, b_pg, b_out, Wh_h16, enc16, W_sT16, Wcat,
                       Wb, A64, attn16, p_gen_g, part, covloss_b, ctrl, dout);
  }
  post_norm<<<CB * CTM1, 256, 0, stream>>>(part, p_gen_g, dout);
  post_tail<<<CB, 256, 0, stream>>>(attn16, p_gen_g, copy_idx, covloss_b,
                                    dout);
}

// Round 17
// 1729.929 us; speedup vs baseline: 1.2168x; 1.0264x over previous
//
#include <hip/hip_runtime.h>
#include <math.h>

// Problem constants
#define CB 16
#define CS 400
#define CT 51
#define CTM1 50
#define CV 50000
#define CE 128
#define CH 256
#define CMAXOOV 50
#define CEXT (CV + CMAXOOV)
#define CX 640             // gate GEMM K = [emb(128)|ctx(256)|h(256)]
#define NST 16             // state blocks
#define NGT 16             // gate blocks (4 batch-groups x 4 unit-slices)
#define NWK 223            // vocab worker blocks
#define NBLK 256
#define NTILE 782          // ceil(V/64)

typedef __attribute__((ext_vector_type(4))) float f32x4;
typedef __attribute__((ext_vector_type(8))) short short8;
typedef unsigned int U32;
typedef unsigned long long U64;

__device__ __forceinline__ float wave_sum(float x) {
#pragma unroll
  for (int o = 32; o > 0; o >>= 1) x += __shfl_xor(x, o);
  return x;
}
__device__ __forceinline__ float sigm(float x) {
  return 1.f / (1.f + __expf(-x));
}
__device__ __forceinline__ float ftanh(float x) {
  x = fminf(fmaxf(x, -15.f), 15.f);
  float e = __expf(2.f * x);
  return (e - 1.f) / (e + 1.f);
}
__device__ __forceinline__ unsigned short f2bf(float f) {
  union { float f; U32 u; } x;
  x.f = f;
  U32 r = x.u + 0x7FFFu + ((x.u >> 16) & 1u);  // RNE
  return (unsigned short)(r >> 16);
}
__device__ __forceinline__ float bf2f(unsigned short u) {
  return __uint_as_float(((U32)u) << 16);
}
__device__ __forceinline__ U64 pack4(float a, float b, float c, float d) {
  return (U64)f2bf(a) | ((U64)f2bf(b) << 16) | ((U64)f2bf(c) << 32) |
         ((U64)f2bf(d) << 48);
}
// uncached (device-coherent) ops — flags, publishes, and fresh-critical reads
__device__ __forceinline__ U32 ald32(const U32* p) {
  return __hip_atomic_load(p, __ATOMIC_RELAXED, __HIP_MEMORY_SCOPE_AGENT);
}
__device__ __forceinline__ U64 ald64(const U64* p) {
  return __hip_atomic_load(p, __ATOMIC_RELAXED, __HIP_MEMORY_SCOPE_AGENT);
}
__device__ __forceinline__ void ast32(U32* p, U32 v) {
  __hip_atomic_store(p, v, __ATOMIC_RELAXED, __HIP_MEMORY_SCOPE_AGENT);
}
__device__ __forceinline__ void ast64(U64* p, U64 v) {
  __hip_atomic_store(p, v, __ATOMIC_RELAXED, __HIP_MEMORY_SCOPE_AGENT);
}
#define VM0 asm volatile("s_waitcnt vmcnt(0)" ::: "memory")

// ---------------------------------------------------------------------------
// One-time weight prep
// ---------------------------------------------------------------------------
__global__ __launch_bounds__(256) void pw_convert(
    const float* __restrict__ W, unsigned short* __restrict__ Wb) {
  size_t i = ((size_t)blockIdx.x * 256 + threadIdx.x) * 8;
  float4 a = *(const float4*)(W + i);
  float4 b = *(const float4*)(W + i + 4);
  short8 o;
  o[0] = (short)f2bf(a.x); o[1] = (short)f2bf(a.y);
  o[2] = (short)f2bf(a.z); o[3] = (short)f2bf(a.w);
  o[4] = (short)f2bf(b.x); o[5] = (short)f2bf(b.y);
  o[6] = (short)f2bf(b.z); o[7] = (short)f2bf(b.w);
  *(short8*)(Wb + i) = o;
}

// Wcat[j][k] bf16 row-major [1024][640]: k<384 -> W_ih[j][k], else W_hh.
__global__ __launch_bounds__(256) void pw_cat(
    const float* __restrict__ W_ih, const float* __restrict__ W_hh,
    unsigned short* __restrict__ Wcat) {
  int t8 = blockIdx.x * 256 + threadIdx.x;  // 81920 short8
  int j = t8 / 80, k8 = t8 % 80;
  short8 o;
#pragma unroll
  for (int i = 0; i < 8; ++i) {
    int k = k8 * 8 + i;
    float v = (k < CE + CH) ? W_ih[(size_t)j * (CE + CH) + k]
                            : W_hh[(size_t)j * CH + (k - (CE + CH))];
    o[i] = (short)f2bf(v);
  }
  *(short8*)(Wcat + (size_t)t8 * 8) = o;
}

__global__ __launch_bounds__(256) void pw_t256(const float* __restrict__ in,
                                               float* __restrict__ out) {
  int j = blockIdx.x, k = threadIdx.x;
  out[j * CH + k] = in[k * CH + j];
}

__global__ __launch_bounds__(256) void pw_t256_bf16(
    const float* __restrict__ in, unsigned short* __restrict__ out) {
  int j = blockIdx.x, k = threadIdx.x;
  out[j * CH + k] = f2bf(in[k * CH + j]);
}

__global__ __launch_bounds__(256) void pw_cvt16(
    const float* __restrict__ in, unsigned short* __restrict__ out) {
  size_t i = ((size_t)blockIdx.x * 256 + threadIdx.x) * 8;
  float4 a = *(const float4*)(in + i);
  float4 b = *(const float4*)(in + i + 4);
  short8 o;
  o[0] = (short)f2bf(a.x); o[1] = (short)f2bf(a.y);
  o[2] = (short)f2bf(a.z); o[3] = (short)f2bf(a.w);
  o[4] = (short)f2bf(b.x); o[5] = (short)f2bf(b.y);
  o[6] = (short)f2bf(b.z); o[7] = (short)f2bf(b.w);
  *(short8*)(out + i) = o;
}

// ---------------------------------------------------------------------------
// P0: Wh_h16 (bf16) = enc @ W_h^T; copy_idx.
// ---------------------------------------------------------------------------
__global__ __launch_bounds__(256) void p0_precompute(
    const float* __restrict__ enc, const float* __restrict__ W_hT,
    const int* __restrict__ src_ids, const int* __restrict__ src_oov,
    unsigned short* __restrict__ Wh_h16, int* __restrict__ copy_idx) {
  const int row0 = blockIdx.x * 8, tid = threadIdx.x;
  __shared__ float erT[CH * 8];
#pragma unroll
  for (int i = 0; i < 8; ++i) {
    int idx = tid + i * 256;
    int r = idx >> 8, j = idx & 255;
    erT[j * 8 + r] = enc[(size_t)row0 * CH + idx];
  }
  if (tid < 8) {
    int row = row0 + tid;
    int ov = src_oov[row];
    copy_idx[row] = (ov >= 0) ? (CV + ov) : src_ids[row];
  }
  __syncthreads();
  float acc[8] = {0, 0, 0, 0, 0, 0, 0, 0};
#pragma unroll 4
  for (int j = 0; j < CH; ++j) {
    float w = W_hT[j * CH + tid];
    float4 e0 = *(const float4*)&erT[j * 8];
    float4 e1 = *(const float4*)&erT[j * 8 + 4];
    acc[0] += e0.x * w; acc[1] += e0.y * w; acc[2] += e0.z * w; acc[3] += e0.w * w;
    acc[4] += e1.x * w; acc[5] += e1.y * w; acc[6] += e1.z * w; acc[7] += e1.w * w;
  }
#pragma unroll
  for (int r = 0; r < 8; ++r)
    Wh_h16[(size_t)(row0 + r) * CH + tid] = f2bf(acc[r]);
}

// ---------------------------------------------------------------------------
// Z: zero control words + rowsum partials.
// ctrl: release@256 (64x16) | xrdy@1280 (16x16) | grdy@1536 (16x16)
// ---------------------------------------------------------------------------
__global__ __launch_bounds__(256) void z_init(U32* __restrict__ ctrl,
                                              float* __restrict__ part) {
  int tid = blockIdx.x * 256 + threadIdx.x;
  if (tid < 2048) ctrl[tid] = 0u;
  for (int i = tid; i < CTM1 * CB * 64; i += 256 * 64) part[i] = 0.f;
}

// ---------------------------------------------------------------------------
// MEGA: 16 state + 16 gate (4x4 tiling, minimal critical path)
//       + 1 agg + 223 vocab workers.  (identical to round-16 passing version)
// ---------------------------------------------------------------------------
__global__ __launch_bounds__(1024, 4) void mega(
    const int* __restrict__ tgt, const float* __restrict__ hidden,
    const float* __restrict__ cell, const int* __restrict__ src_lens,
    const float* __restrict__ embedding, const float* __restrict__ w_c,
    const float* __restrict__ v_vec, const float* __restrict__ b_attn,
    const float* __restrict__ b_ih, const float* __restrict__ b_hh,
    const float* __restrict__ W_pg, const float* __restrict__ b_pg,
    const float* __restrict__ b_out,
    const unsigned short* __restrict__ Wh_h16,
    const unsigned short* __restrict__ enc16,
    const unsigned short* __restrict__ W_sT16,
    const unsigned short* __restrict__ Wcat,
    const unsigned short* __restrict__ Wb, U64* __restrict__ A64,
    unsigned short* __restrict__ attn16, float* __restrict__ p_gen_g,
    float* __restrict__ part, float* __restrict__ covloss_b,
    U32* __restrict__ ctrl, float* __restrict__ dout) {
  const int bid = blockIdx.x, tid = threadIdx.x;
  const int lane = tid & 63, wv = tid >> 6;  // 16 waves
  U32* release = ctrl + 256;    // 64 worker replicas
  U32* xrdy = ctrl + 1280;      // state: ctx published
  U32* grdy = ctrl + 1536;      // gate: h slice published

  __shared__ __align__(16) U64 sh_big[2592];
  __shared__ float cov_s[CS];
  __shared__ float a_s[CS];
  __shared__ __align__(16) float h_cur[CH];
  __shared__ float hws_s[CH];
  __shared__ __align__(16) float ctx_s[CH];
  __shared__ float emb_s[CE];
  __shared__ float pctx[4 * CH];
  __shared__ float gsl[4][4][64];             // gate: [g2][b][u_loc]
  __shared__ int sh_tok[CB];
  __shared__ float red[16];
  __shared__ float stat[4];
  __shared__ float prs[16][16];

  if (bid < NST) {
    // ================= STATE LANE (batch b), 16 waves =================
    const int b = bid;
    const int gi = b >> 2;  // batch group
    const int len = src_lens[b];
    const float ba = b_attn[0];
    const int k4 = lane * 4;
    const float4 wc4 = *(const float4*)(w_c + k4);
    const float4 vv4 = *(const float4*)(v_vec + k4);
    const int kg = tid & 255, grp = tid >> 8;
    float covl = 0.f;

    if (tid < CS) { cov_s[tid] = 0.f; a_s[tid] = 0.f; }
    if (tid < CH) h_cur[tid] = hidden[b * CH + tid];
    __syncthreads();
    {  // one-time hWs init from h0
      float acc = 0.f;
#pragma unroll 8
      for (int j = grp * 64; j < grp * 64 + 64; ++j)
        acc += h_cur[j] * bf2f(W_sT16[j * CH + kg]);
      pctx[grp * CH + kg] = acc;
    }
    __syncthreads();
    if (tid < CH)
      hws_s[tid] = pctx[tid] + pctx[CH + tid] + pctx[2 * CH + tid] +
                   pctx[3 * CH + tid];
    __syncthreads();

    for (int t = 0; t < CTM1; ++t) {
      // ---- phase A ----
      if (t > 0) {
        if (tid < CS) {
          float a = a_s[tid], cv = cov_s[tid];
          covl += fminf(a, cv);
          cov_s[tid] = cv + a;
        }
        __syncthreads();
      }
      float ps = 0.f;
      for (int s = wv; s < len; s += 16) {  // len-clamped (a_s[>=len]==0)
        float cv = cov_s[s];
        U64 wq = *(const U64*)(Wh_h16 + ((size_t)(b * CS + s)) * CH + k4);
        float p =
            ftanh(bf2f((unsigned short)wq) + hws_s[k4] + cv * wc4.x + ba) *
                vv4.x +
            ftanh(bf2f((unsigned short)(wq >> 16)) + hws_s[k4 + 1] +
                  cv * wc4.y + ba) *
                vv4.y +
            ftanh(bf2f((unsigned short)(wq >> 32)) + hws_s[k4 + 2] +
                  cv * wc4.z + ba) *
                vv4.z +
            ftanh(bf2f((unsigned short)(wq >> 48)) + hws_s[k4 + 3] +
                  cv * wc4.w + ba) *
                vv4.w;
        p = wave_sum(p);
        if (lane == 0) {
          float e = __expf(p);  // |score| <~ 10: no-max softmax safe
          a_s[s] = e;
          ps += e;
        }
      }
      if (lane == 0) red[wv] = ps;
      __syncthreads();
      if (tid == 0) {
        float s2 = 0.f;
#pragma unroll
        for (int i = 0; i < 16; ++i) s2 += red[i];
        stat[0] = 1.f / s2;
      }
      __syncthreads();
      const float inv = stat[0];
      if (tid < CS) {
        float a = a_s[tid] * inv;   // 0 for s>=len
        a_s[tid] = a;
        attn16[((size_t)t * CB + b) * CS + tid] = f2bf(a);
      }
      __syncthreads();
      {  // ctx partials (len-clamped per group)
        float pc = 0.f;
        int hi = len - grp * 100;
        hi = (hi < 0) ? 0 : ((hi > 100) ? 100 : hi);
        const unsigned short* er =
            enc16 + ((size_t)(b * CS + grp * 100)) * CH + kg;
        for (int i = 0; i < hi; ++i)
          pc += a_s[grp * 100 + i] * bf2f(er[(size_t)i * CH]);
        pctx[grp * CH + kg] = pc;
      }
      __syncthreads();
      if (tid < CH)
        ctx_s[tid] = pctx[tid] + pctx[CH + tid] + pctx[2 * CH + tid] +
                     pctx[3 * CH + tid];
      if (tid < CE)
        emb_s[tid] = embedding[(size_t)tgt[b * CT + t] * CE + tid];
      __syncthreads();
      if (tid < 64) {  // publish ctx -> A64 ctx-half (UC)
        ast64(&A64[(size_t)t * 2048 + b * 128 + 64 + tid],
              pack4(ctx_s[4 * tid], ctx_s[4 * tid + 1], ctx_s[4 * tid + 2],
                    ctx_s[4 * tid + 3]));
      }
      VM0;
      __syncthreads();
      if (tid == 0) ast32(&xrdy[b * 16], (U32)(t + 1));
      // ---- wait own-group gate slices (4 flags) ----
      if (wv == 0) {
        int gg = 0;
        while (gg < (1 << 22)) {
          U32 v = (lane < 4) ? ald32(&grdy[(gi * 4 + lane) * 16])
                             : (U32)(t + 1);
          if (__all(v >= (U32)(t + 1))) break;
          __builtin_amdgcn_s_sleep(1);
          ++gg;
        }
      }
      __syncthreads();
      // ---- phase C: stage h from A64 h-half via UC (fresh!), hWs, p_gen ----
      if (tid < 64) {
        U64 v = ald64(&A64[(size_t)t * 2048 + b * 128 + tid]);
        h_cur[4 * tid] = bf2f((unsigned short)v);
        h_cur[4 * tid + 1] = bf2f((unsigned short)(v >> 16));
        h_cur[4 * tid + 2] = bf2f((unsigned short)(v >> 32));
        h_cur[4 * tid + 3] = bf2f((unsigned short)(v >> 48));
      }
      __syncthreads();
      {
        float acc = 0.f;
#pragma unroll 8
        for (int j = grp * 64; j < grp * 64 + 64; ++j)
          acc += h_cur[j] * bf2f(W_sT16[j * CH + kg]);
        pctx[grp * CH + kg] = acc;
      }
      __syncthreads();
      if (tid < CH)
        hws_s[tid] = pctx[tid] + pctx[CH + tid] + pctx[2 * CH + tid] +
                     pctx[3 * CH + tid];
      {
        float z = 0.f;
        if (tid < CH)
          z = h_cur[tid] * W_pg[tid] + ctx_s[tid] * W_pg[CH + tid];
        if (tid < CE) z += emb_s[tid] * W_pg[2 * CH + tid];
        z = wave_sum(z);
        if (lane == 0) red[wv] = z;
        __syncthreads();
        if (tid == 0) {
          float s2 = 0.f;
#pragma unroll
          for (int i = 0; i < 16; ++i) s2 += red[i];
          p_gen_g[t * CB + b] = sigm(s2 + b_pg[0]);
        }
      }
      __syncthreads();
    }
    // tail: covloss t=49 + totals (hT/cT written by gate blocks)
    if (tid < CS) covl += fminf(a_s[tid], cov_s[tid]);
    covl = wave_sum(covl);
    if (lane == 0) red[wv] = covl;
    __syncthreads();
    if (tid == 0) {
      float s2 = 0.f;
#pragma unroll
      for (int i = 0; i < 16; ++i) s2 += red[i];
      covloss_b[b] = s2;
    }
  } else if (bid < NST + NGT) {
    // ===== GATE BLOCKS (i=batch group, j=unit slice of 64 units) =====
    const int g = bid - NST;
    const int gi = g >> 2, gj = g & 3;
    const int b0 = gi * 4, u0 = gj * 64;
    const int nn = lane & 15, gq = lane >> 4;
    U64* xg64 = sh_big;                  // rows [4][162] u64 (= [4][648] sh)
    short* xg_s = (short*)sh_big;
    const short8* x8 = (const short8*)sh_big;
    const int g2 = wv >> 2;
    const int ncol = g2 * 256 + u0 + (wv & 3) * 16 + nn;
    const short8* bp = (const short8*)Wcat + (size_t)ncol * 80;
    const int cbL = wv, cu = lane;       // valid when wv<4
    float c_reg = 0.f, bi0 = 0.f, bi1 = 0.f, bi2 = 0.f, bi3 = 0.f;
    if (wv < 4) {
      c_reg = cell[(b0 + cbL) * CH + u0 + cu];
      bi0 = b_ih[u0 + cu] + b_hh[u0 + cu];
      bi1 = b_ih[CH + u0 + cu] + b_hh[CH + u0 + cu];
      bi2 = b_ih[2 * CH + u0 + cu] + b_hh[2 * CH + u0 + cu];
      bi3 = b_ih[3 * CH + u0 + cu] + b_hh[3 * CH + u0 + cu];
    }
    for (int t = 0; t < CTM1; ++t) {
      // -- precompute window (overlaps state phase A) --
      if (t > 0 && wv == 0) {  // own group's h(t-1) slices visible?
        int gg = 0;
        while (gg < (1 << 22)) {
          U32 v = (lane < 4) ? ald32(&grdy[(gi * 4 + lane) * 16]) : (U32)t;
          if (__all(v >= (U32)t)) break;
          __builtin_amdgcn_s_sleep(1);
          ++gg;
        }
      }
      if (tid < 4) sh_tok[tid] = tgt[(b0 + tid) * CT + t];
      __syncthreads();
      // x row (shorts): emb 0..127 | ctx 128..383 | h 384..639
      //         (u64):  emb 0..31  | ctx 32..95   | h 96..159
      if (tid < 512) {
        int bb = tid >> 7, k = tid & 127;
        xg_s[bb * 648 + k] =
            (short)f2bf(embedding[(size_t)sh_tok[bb] * CE + k]);
      }
      if (t == 0) {
        if (tid < 1024) {
          int bb = tid >> 8, k = tid & 255;
          xg_s[bb * 648 + 384 + k] = (short)f2bf(hidden[(b0 + bb) * CH + k]);
        }
      } else {
        if (tid < 256) {  // stage h(t-1) via UC (fresh) at u64 96..159
          int bb = tid >> 6, iu = tid & 63;
          xg64[bb * 162 + 96 + iu] =
              ald64(&A64[(size_t)(t - 1) * 2048 + (b0 + bb) * 128 + iu]);
        }
      }
      __syncthreads();
      f32x4 acc = {0.f, 0.f, 0.f, 0.f};
      {  // emb part kt 0..3, h part kt 12..19 (pre-ctx)
#pragma unroll
        for (int kt = 0; kt < 4; ++kt)
          acc = __builtin_amdgcn_mfma_f32_16x16x32_bf16(
              x8[nn * 81 + kt * 4 + gq], bp[kt * 4 + gq], acc, 0, 0, 0);
#pragma unroll
        for (int kt = 12; kt < 20; ++kt)
          acc = __builtin_amdgcn_mfma_f32_16x16x32_bf16(
              x8[nn * 81 + kt * 4 + gq], bp[kt * 4 + gq], acc, 0, 0, 0);
      }
      // -- wait ctx from own group's 4 state blocks --
      if (wv == 0) {
        int gg = 0;
        while (gg < (1 << 22)) {
          U32 v = (lane < 4) ? ald32(&xrdy[(b0 + lane) * 16]) : (U32)(t + 1);
          if (__all(v >= (U32)(t + 1))) break;
          __builtin_amdgcn_s_sleep(1);
          ++gg;
        }
      }
      __syncthreads();
      if (tid < 256) {  // stage ctx via UC (fresh) at u64 32..95
        int bb = tid >> 6, iu = tid & 63;
        xg64[bb * 162 + 32 + iu] =
            ald64(&A64[(size_t)t * 2048 + (b0 + bb) * 128 + 64 + iu]);
      }
      __syncthreads();
      {  // ctx part kt 4..11
#pragma unroll
        for (int kt = 4; kt < 12; ++kt)
          acc = __builtin_amdgcn_mfma_f32_16x16x32_bf16(
              x8[nn * 81 + kt * 4 + gq], bp[kt * 4 + gq], acc, 0, 0, 0);
        if (gq == 0) {  // valid D rows m=0..3 (batches)
#pragma unroll
          for (int r = 0; r < 4; ++r)
            gsl[g2][r][(wv & 3) * 16 + nn] = acc[r];
        }
      }
      __syncthreads();
      if (wv < 4) {  // cell update + publish h (bf16 A64; fp32 hT at t=49)
        float gi_ = gsl[0][cbL][cu] + bi0;
        float gf = gsl[1][cbL][cu] + bi1;
        float gg2 = gsl[2][cbL][cu] + bi2;
        float go = gsl[3][cbL][cu] + bi3;
        float cn = sigm(gf) * c_reg + sigm(gi_) * ftanh(gg2);
        c_reg = cn;
        float hn = sigm(go) * ftanh(cn);
        if (t == CTM1 - 1) {  // exact fp32 hT straight to dout
          const size_t D0 = (size_t)CB * CTM1 * CEXT;
          dout[D0 + (b0 + cbL) * CH + u0 + cu] = hn;
        }
        float h1 = __shfl_down(hn, 1);
        float h2 = __shfl_down(hn, 2);
        float h3 = __shfl_down(hn, 3);
        if (!(cu & 3))
          ast64(&A64[(size_t)t * 2048 + (b0 + cbL) * 128 + gj * 16 +
                     (cu >> 2)],
                pack4(hn, h1, h2, h3));
      }
      VM0;
      __syncthreads();
      if (tid == 0) ast32(&grdy[g * 16], (U32)(t + 1));
    }
    // tail: cT slice (exact fp32)
    if (wv < 4) {
      const size_t D0 = (size_t)CB * CTM1 * CEXT;
      dout[D0 + CB * CH + (b0 + cbL) * CH + u0 + cu] = c_reg;
    }
  } else if (bid == NST + NGT) {
    // ===================== AGGREGATOR (1 block) ==========================
    for (int t = 0; t < CTM1; ++t) {
      if (wv == 0) {
        int gg = 0;
        while (gg < (1 << 22)) {
          U32 v = (lane < NGT) ? ald32(&grdy[lane * 16]) : (U32)(t + 1);
          if (__all(v >= (U32)(t + 1))) break;
          __builtin_amdgcn_s_sleep(4);
          ++gg;
        }
      }
      __syncthreads();
      if (tid < 64) ast32(&release[tid * 16], (U32)(t + 1));
      __syncthreads();
    }
  } else {
    // ============ VOCAB WORKERS (223 blocks, 16 waves, 4 tiles) ==========
    const int vb = bid - NST - NGT - 1;
    const int rep = vb & 63;
    const int nn = lane & 15, g = lane >> 4;
    const int t4 = (wv >> 2) * NWK + vb;
    const int v = t4 * 64 + (wv & 3) * 16 + nn;
    const bool live = (t4 < NTILE) && (v < CV);
    const int vc = live ? v : CV - 1;
    U64* a64l = sh_big;  // [16][130] u64
    const short8* lds8 = (const short8*)sh_big;
    const short8* bp = (const short8*)Wb + (size_t)vc * 64;
    const float bo = live ? b_out[v] : 0.f;
    for (int t = 0; t < CTM1; ++t) {
      if (tid == 0) {
        int gg = 0;
        while (ald32(&release[rep * 16]) < (U32)(t + 1) && ++gg < (1 << 18))
          __builtin_amdgcn_s_sleep(32);
      }
      __syncthreads();
      {  // stage A slab cached (validated across r9-r16)
        const U64* src = A64 + (size_t)t * 2048;
#pragma unroll
        for (int i = 0; i < 2; ++i) {
          int idx = tid + i * 1024;
          int row = idx >> 7, col = idx & 127;
          a64l[row * 130 + col] = src[idx];
        }
      }
      __syncthreads();
      short8 af[16];
#pragma unroll
      for (int kt = 0; kt < 16; ++kt) af[kt] = lds8[nn * 65 + kt * 4 + g];
      f32x4 acc = {0.f, 0.f, 0.f, 0.f};
#pragma unroll
      for (int kt = 0; kt < 16; ++kt)
        acc = __builtin_amdgcn_mfma_f32_16x16x32_bf16(af[kt], bp[kt * 4 + g],
                                                      acc, 0, 0, 0);
      float ev[4];
#pragma unroll
      for (int r = 0; r < 4; ++r) {
        float e = live ? __expf(acc[r] + bo) : 0.f;
        if (live) dout[((size_t)((g * 4 + r) * CTM1 + t)) * CEXT + v] = e;
#pragma unroll
        for (int o = 1; o < 16; o <<= 1) e += __shfl_xor(e, o);
        ev[r] = e;
      }
      if (nn == 0) {
#pragma unroll
        for (int r = 0; r < 4; ++r) prs[wv][g * 4 + r] = ev[r];
      }
      __syncthreads();
      if (tid < 16) {
        float s = 0.f;
#pragma unroll
        for (int w = 0; w < 16; ++w) s += prs[w][tid];
        atomicAdd(&part[((size_t)t * CB + tid) * 64 + rep], s);
      }
      __syncthreads();
    }
  }
}

// ---------------------------------------------------------------------------
// POST (merged): per (b,t) row — reduce 64 rowsum partials, normalize + zero
// pads, then this row's 400-element copy-dist scatter.  Block 0: covloss.
// grid = 800, 256 threads.
// ---------------------------------------------------------------------------
__global__ __launch_bounds__(256) void post_all(
    const float* __restrict__ part, const float* __restrict__ p_gen_g,
    const unsigned short* __restrict__ attn16,
    const int* __restrict__ copy_idx, const float* __restrict__ covloss_b,
    float* __restrict__ dout) {
  const int R = blockIdx.x;
  const int b = R / CTM1, t = R % CTM1;
  const int tid = threadIdx.x;
  __shared__ float stat[2];
  float s = (tid < 64) ? part[((size_t)t * CB + b) * 64 + tid] : 0.f;
  s = wave_sum(s);
  if (tid == 0) {
    float pg = p_gen_g[t * CB + b];
    stat[0] = pg / s;        // normalize factor
    stat[1] = 1.f - pg;      // copy weight
  }
  __syncthreads();
  const float inv = stat[0], pg1 = stat[1];
  float* drow = dout + (size_t)R * CEXT;
  for (int v = tid; v < CEXT; v += 256)
    drow[v] = (v < CV) ? drow[v] * inv : 0.f;
  __syncthreads();  // row fully normalized before scatter into it
  const unsigned short* ar = attn16 + ((size_t)t * CB + b) * CS;
  for (int sIdx = tid; sIdx < CS; sIdx += 256)
    atomicAdd(drow + copy_idx[b * CS + sIdx], pg1 * bf2f(ar[sIdx]));
  if (R == 0 && tid == 0) {
    const size_t D0 = (size_t)CB * CTM1 * CEXT;
    float c = 0.f;
    for (int i = 0; i < CB; ++i) c += covloss_b[i];
    dout[D0 + 2 * CB * CH] = c / (float)(CTM1 * CB);
  }
}

// ---------------------------------------------------------------------------
extern "C" void kernel_launch(void* const* d_in, const int* in_sizes, int n_in,
                              void* d_out, int out_size, void* d_ws,
                              size_t ws_size, hipStream_t stream) {
  const int* tgt = (const int*)d_in[0];
  const float* hidden = (const float*)d_in[1];
  const float* cell = (const float*)d_in[2];
  const float* enc = (const float*)d_in[3];
  const int* src_lens = (const int*)d_in[4];
  const int* src_ids = (const int*)d_in[5];
  const int* src_oov = (const int*)d_in[6];
  const float* embedding = (const float*)d_in[7];
  const float* W_h = (const float*)d_in[8];
  const float* W_s = (const float*)d_in[9];
  const float* w_c = (const float*)d_in[10];
  const float* v_vec = (const float*)d_in[11];
  const float* b_attn = (const float*)d_in[12];
  const float* W_ih = (const float*)d_in[13];
  const float* W_hh = (const float*)d_in[14];
  const float* b_ih = (const float*)d_in[15];
  const float* b_hh = (const float*)d_in[16];
  const float* W_pg = (const float*)d_in[17];
  const float* b_pg = (const float*)d_in[18];
  const float* W_out = (const float*)d_in[19];
  const float* b_out = (const float*)d_in[20];
  float* dout = (float*)d_out;

  // workspace layout (word count before u64 region is even)
  float* ws = (float*)d_ws;
  float* W_hT = ws;                                  // 65,536 f
  float* p_gen_g = W_hT + CH * CH;                   // 800 f
  float* part = p_gen_g + CTM1 * CB;                 // 51,200 f
  float* covloss_b = part + CTM1 * CB * 64;          // 16 f
  int* copy_idx = (int*)(covloss_b + 16);            // 6,400 i
  U32* ctrl = (U32*)(copy_idx + CB * CS);            // 2,048 u32
  U64* A64 = (U64*)(ctrl + 2048);                    // 102,400 u64
  unsigned short* attn16 =
      (unsigned short*)(A64 + (size_t)CTM1 * 2048);  // 320,000 sh
  unsigned short* Wh_h16 = attn16 + (size_t)CTM1 * CB * CS;  // 1,638,400 sh
  unsigned short* enc16 = Wh_h16 + (size_t)CB * CS * CH;     // 1,638,400 sh
  unsigned short* W_sT16 = enc16 + (size_t)CB * CS * CH;     // 65,536 sh
  unsigned short* Wcat = W_sT16 + CH * CH;           // 655,360 sh
  unsigned short* Wb = Wcat + (size_t)(4 * CH) * CX; // 25,600,000 sh

  z_init<<<64, 256, 0, stream>>>(ctrl, part);
  pw_convert<<<(CV * 2 * CH) / (256 * 8), 256, 0, stream>>>(W_out, Wb);
  pw_cat<<<((4 * CH) * CX / 8) / 256, 256, 0, stream>>>(W_ih, W_hh, Wcat);
  pw_t256<<<CH, CH, 0, stream>>>(W_h, W_hT);
  pw_t256_bf16<<<CH, CH, 0, stream>>>(W_s, W_sT16);
  pw_cvt16<<<(CB * CS * CH) / (256 * 8), 256, 0, stream>>>(enc, enc16);
  p0_precompute<<<CB * CS / 8, 256, 0, stream>>>(enc, W_hT, src_ids, src_oov,
                                                 Wh_h16, copy_idx);

  void* kargs[] = {
      (void*)&tgt,      (void*)&hidden,    (void*)&cell,    (void*)&src_lens,
      (void*)&embedding,(void*)&w_c,       (void*)&v_vec,   (void*)&b_attn,
      (void*)&b_ih,     (void*)&b_hh,      (void*)&W_pg,    (void*)&b_pg,
      (void*)&b_out,    (void*)&Wh_h16,    (void*)&enc16,   (void*)&W_sT16,
      (void*)&Wcat,     (void*)&Wb,        (void*)&A64,     (void*)&attn16,
      (void*)&p_gen_g,  (void*)&part,      (void*)&covloss_b,(void*)&ctrl,
      (void*)&dout};
  hipError_t e = hipLaunchCooperativeKernel((const void*)mega, dim3(NBLK),
                                            dim3(1024), kargs, 0, stream);
  if (e != hipSuccess) {
    hipLaunchKernelGGL(mega, dim3(NBLK), dim3(1024), 0, stream, tgt, hidden,
                       cell, src_lens, embedding, w_c, v_vec, b_attn, b_ih,
                       b_hh, W_pg, b_pg, b_out, Wh_h16, enc16, W_sT16, Wcat,
                       Wb, A64, attn16, p_gen_g, part, covloss_b, ctrl, dout);
  }
  post_all<<<CB * CTM1, 256, 0, stream>>>(part, p_gen_g, attn16, copy_idx,
                                          covloss_b, dout);
}